// Round 2
// baseline (386.087 us; speedup 1.0000x reference)
//
#include <hip/hip_runtime.h>
#include <math.h>

typedef __bf16 bf16x8 __attribute__((ext_vector_type(8)));
typedef __bf16 bf16x4 __attribute__((ext_vector_type(4)));
typedef float f32x4 __attribute__((ext_vector_type(4)));

#define HD 1024
#define SEQ 2048
#define NB 4
#define WEL (HD * HD)   // elements per weight matrix

// Load 8 contiguous elements as bf16x8, converting f32 -> bf16 if needed.
__device__ inline bf16x8 load8cvt(const __bf16* p) { return *(const bf16x8*)p; }
__device__ inline bf16x8 load8cvt(const float* p) {
    f32x4 a = *(const f32x4*)p;
    f32x4 b = *(const f32x4*)(p + 4);
    bf16x8 r;
#pragma unroll
    for (int i = 0; i < 4; ++i) { r[i] = (__bf16)a[i]; r[i + 4] = (__bf16)b[i]; }
    return r;
}

// Load 4 contiguous elements as f32x4 (from f32 or bf16 source).
__device__ inline f32x4 load4f(const float* p) { return *(const f32x4*)p; }
__device__ inline f32x4 load4f(const __bf16* p) {
    bf16x4 v = *(const bf16x4*)p;
    f32x4 r;
#pragma unroll
    for (int i = 0; i < 4; ++i) r[i] = (float)v[i];
    return r;
}

// Async global->LDS, 16 bytes per lane (global_load_lds_dwordx4).
__device__ inline void gld_lds16(const void* g, void* l) {
    __builtin_amdgcn_global_load_lds(
        (const __attribute__((address_space(1))) unsigned int*)g,
        (__attribute__((address_space(3))) unsigned int*)l, 16, 0, 0);
}

// ===========================================================================
// Legacy 128x128 structure (kept for ctx GEMM + f32 fallback proj)
// ===========================================================================
template <typename T>
__device__ inline void stage_tile(const T* __restrict__ G, int ld, __bf16* s, int tid)
{
    const int r  = tid >> 3;                          // 0..31
    const int co = ((tid & 7) ^ (r & 7)) * 8;         // swizzled source column
    if constexpr (sizeof(T) == 2) {
        __bf16* dst = s + (tid >> 6) * 512;           // wave-uniform base
#pragma unroll
        for (int c = 0; c < 4; ++c)
            gld_lds16(G + (long)(c * 32 + r) * ld + co, dst + c * 2048);
    } else {
#pragma unroll
        for (int c = 0; c < 4; ++c)
            *(bf16x8*)(s + c * 2048 + tid * 8) = load8cvt(G + (long)(c * 32 + r) * ld + co);
    }
}

__device__ inline bf16x8 frag_read(const __bf16* s, int row, int c)
{
    return *(const bf16x8*)&s[row * 64 + ((c ^ (row & 7)) * 8)];
}

__device__ inline void mfma_ktile(const __bf16* __restrict__ sa,
                                  const __bf16* __restrict__ sb,
                                  int wm, int wn, int l15, int quad,
                                  f32x4 (&acc)[4][4])
{
#pragma unroll
    for (int kk = 0; kk < 64; kk += 32) {
        const int c8 = quad + (kk >> 3);
        bf16x8 af[4], bf[4];
#pragma unroll
        for (int i = 0; i < 4; ++i)
            af[i] = frag_read(sa, wm + i * 16 + l15, c8);
#pragma unroll
        for (int j = 0; j < 4; ++j)
            bf[j] = frag_read(sb, wn + j * 16 + l15, c8);
#pragma unroll
        for (int i = 0; i < 4; ++i)
#pragma unroll
            for (int j = 0; j < 4; ++j)
                acc[i][j] = __builtin_amdgcn_mfma_f32_16x16x32_bf16(af[i], bf[j], acc[i][j], 0, 0, 0);
    }
}

// ===========================================================================
// 256x256 8-phase pipelined GEMM core (HK/m201 template, plain HIP).
//
// Geometry: BM=BN=256, BK=64 (as two K-halves of 32), 8 waves (2 Mrow x 4
// Ncol), per-wave C = 128x64 = acc[8][4] f32x4. LDS = 128 KiB: per operand
// 2 buffers x 2 K-halves x (256 rows x 32 bf16 = 16 KiB).
//
// Per phase: {4 or 8 ds_read_b128} + {stage one 16 KiB half (2 x
// global_load_lds_dwordx4 per thread)} + [vmcnt(4) at P4/P8 only] +
// s_barrier + lgkmcnt(0) + setprio(1) + 16 MFMA + setprio(0) + s_barrier.
//
// Stage stagger (iteration computes tiles Tc=even from buf0 P1-4, Tc+1 from
// buf1 P5-8); each stage issues AFTER the barrier retiring its dest's reads:
//   P1: Tc+1.A.h1   P2: Tc+1.B.h1   (buf1 kk1: read until prev P8 barrier)
//   P3: Tc+2.A.h0   P4: Tc+2.B.h0   (buf0 kk0: read until P2 barrier)
//   P5: Tc+2.A.h1   P6: Tc+2.B.h1   (buf0 kk1: read until P4 barrier)
//   P7: Tc+3.A.h0   P8: Tc+3.B.h0   (buf1 kk0: read until P6 barrier)
// vmcnt(4) at P4 forces {prevP7,prevP8,P1,P2} landed (data for P5/P7);
// vmcnt(4) at P8 forces {P3..P6} landed (data for next P1/P3). Final
// iteration uses vmcnt(0) at P4 (its P1/P2 stages are needed at P7 and the
// later stages are skipped, so the steady-state count no longer covers them).
//
// LDS read swizzle: row is 64B = 4 chunks of 16B; chunk_lds = chunk ^
// ((row>>1)&3) -> a frag read (16 rows x same chunk, 4 quads) is 2-way bank
// aliased = free (m136). global_load_lds dest is linear, so the INVERSE
// permutation is applied to the per-lane global source (G21).
// ===========================================================================
__device__ __forceinline__ bf16x8 frag8(const __bf16* s, int row, int quad)
{
    return *(const bf16x8*)&s[row * 32 + ((quad ^ ((row >> 1) & 3)) * 8)];
}

// Stage one 256-row x 32-col bf16 half-tile into LDS (linear dest).
__device__ __forceinline__ void stage_half(const __bf16* __restrict__ G, int ld,
                                           __bf16* s, int tid)
{
    const int row = tid >> 2;                                   // 0..127
    const int csw = ((tid & 3) ^ ((tid >> 3) & 3)) * 8;         // swizzled chunk
    __bf16* dst = s + (tid >> 6) * 512;                          // wave base
    gld_lds16(G + (long)row * ld + csw, dst);
    gld_lds16(G + (long)(row + 128) * ld + csw, dst + 4096);
}

#define VM4 asm volatile("s_waitcnt vmcnt(4)" ::: "memory")
#define VM0 asm volatile("s_waitcnt vmcnt(0)" ::: "memory")

#define PHASE(SAH, SBH, IH, LOADB, STAGE_STMT, VM_STMT)                         \
    {                                                                           \
        bf16x8 af_[4];                                                          \
        _Pragma("unroll") for (int i_ = 0; i_ < 4; ++i_)                        \
            af_[i_] = frag8(SAH, wr * 128 + ((IH) * 4 + i_) * 16 + l15, quad);  \
        if (LOADB) {                                                            \
            _Pragma("unroll") for (int j_ = 0; j_ < 4; ++j_)                    \
                bf[j_] = frag8(SBH, wc * 64 + j_ * 16 + l15, quad);             \
        }                                                                       \
        STAGE_STMT;                                                             \
        VM_STMT;                                                                \
        __builtin_amdgcn_s_barrier();                                           \
        asm volatile("s_waitcnt lgkmcnt(0)" ::: "memory");                      \
        __builtin_amdgcn_sched_barrier(0);                                      \
        __builtin_amdgcn_s_setprio(1);                                          \
        _Pragma("unroll") for (int i_ = 0; i_ < 4; ++i_)                        \
        _Pragma("unroll") for (int j_ = 0; j_ < 4; ++j_)                        \
            acc[(IH) * 4 + i_][j_] = __builtin_amdgcn_mfma_f32_16x16x32_bf16(   \
                af_[i_], bf[j_], acc[(IH) * 4 + i_][j_], 0, 0, 0);              \
        __builtin_amdgcn_s_setprio(0);                                          \
        __builtin_amdgcn_s_barrier();                                           \
    }

__device__ __forceinline__ void kloop256(
    const __bf16* __restrict__ Ag, int lda,
    const __bf16* __restrict__ Bg, int ldb,
    int NT, __bf16* lds, int tid, f32x4 (&acc)[8][4])
{
    const int lane = tid & 63;
    const int l15  = lane & 15;
    const int quad = lane >> 4;
    const int wave = tid >> 6;
    const int wr = wave >> 2;       // 0..1
    const int wc = wave & 3;        // 0..3

    auto SA = [&](int b, int h) { return lds + (b * 2 + h) * 8192; };
    auto SB = [&](int b, int h) { return lds + 32768 + (b * 2 + h) * 8192; };
    auto stA = [&](int t, int h) {
        if (t < NT) stage_half(Ag + t * 64 + h * 32, lda, SA(t & 1, h), tid);
    };
    auto stB = [&](int t, int h) {
        if (t < NT) stage_half(Bg + t * 64 + h * 32, ldb, SB(t & 1, h), tid);
    };

    // prologue: T0 complete + T1 kk0; force T0 landed (leave T1.kk0 in flight)
    stA(0, 0); stB(0, 0); stA(0, 1); stB(0, 1); stA(1, 0); stB(1, 0);
    VM4;
    __builtin_amdgcn_s_barrier();

    bf16x8 bf[4];
    for (int c = 0; c < NT; c += 2) {
        const bool last = (c + 2 >= NT);
        PHASE(SA(0, 0), SB(0, 0), 0, true,  (stA(c + 1, 1)), (void)0);
        PHASE(SA(0, 0), SB(0, 0), 1, false, (stB(c + 1, 1)), (void)0);
        PHASE(SA(0, 1), SB(0, 1), 0, true,  (stA(c + 2, 0)), (void)0);
        PHASE(SA(0, 1), SB(0, 1), 1, false, (stB(c + 2, 0)),
              if (last) { VM0; } else { VM4; });
        PHASE(SA(1, 0), SB(1, 0), 0, true,  (stA(c + 2, 1)), (void)0);
        PHASE(SA(1, 0), SB(1, 0), 1, false, (stB(c + 2, 1)), (void)0);
        PHASE(SA(1, 1), SB(1, 1), 0, true,  (stA(c + 3, 0)), (void)0);
        PHASE(SA(1, 1), SB(1, 1), 1, false, (stB(c + 3, 0)), VM4);
    }
}

// ---------------------------------------------------------------------------
// Projection GEMM on the 256x256 8-phase core. Grid = 128*nz blocks of 512,
// XCD-remapped: wrk decomposes as z = wrk>>7, n-block = wrk&3, m-block =
// (wrk>>2)&31.
// ---------------------------------------------------------------------------
struct Proj3 {
    const void* A[3];
    const void* W[3];
    const float* bias[3];
    __bf16* C[3];
    int vtmask;
};

__global__ __launch_bounds__(512, 2) void gemm_proj256(Proj3 p)
{
    extern __shared__ __bf16 lds[];    // 128 KiB
    const int tid = threadIdx.x;
    const int L = blockIdx.x;
    const int per = gridDim.x >> 3;
    const int wrk = (L & 7) * per + (L >> 3);
    const int r  = wrk & 127;
    const int z  = wrk >> 7;
    const int n0 = (r & 3) * 256;
    const int m0 = (r >> 2) * 256;
    const bool vt = (p.vtmask >> z) & 1;

    const __bf16* Ag = (const __bf16*)p.A[z] + (long)m0 * HD;
    const __bf16* Wg = (const __bf16*)p.W[z] + (long)n0 * HD;
    const float* bias = p.bias[z];
    __bf16* C = p.C[z];

    f32x4 acc[8][4];
    const f32x4 zero = {0.f, 0.f, 0.f, 0.f};
#pragma unroll
    for (int i = 0; i < 8; ++i)
#pragma unroll
        for (int j = 0; j < 4; ++j) acc[i][j] = zero;

    kloop256(Ag, HD, Wg, HD, HD / 64, lds, tid, acc);

    const int lane = tid & 63, l15 = lane & 15, quad = lane >> 4;
    const int wave = tid >> 6, wr = wave >> 2, wc = wave & 3;
#pragma unroll
    for (int j = 0; j < 4; ++j) {
        const int col = n0 + wc * 64 + j * 16 + l15;
        const float bv = bias[col];
#pragma unroll
        for (int i = 0; i < 8; ++i) {
#pragma unroll
            for (int rr = 0; rr < 4; ++rr) {
                const int row = m0 + wr * 128 + i * 16 + quad * 4 + rr;
                const float v = acc[i][j][rr] + bv;
                if (vt) {
                    C[(((long)(row >> 11) * HD) + col) * SEQ + (row & (SEQ - 1))] = (__bf16)v;
                } else {
                    C[(long)row * HD + col] = (__bf16)v;
                }
            }
        }
    }
}

// ---------------------------------------------------------------------------
// Scores GEMM (k x q^T, causal 256-blocks) on the 8-phase core, fused
// exp/colsum epilogue. Grid = 144 = 4 batches x 36 causal blocks (sb<=tb),
// XCD-remapped.
// ---------------------------------------------------------------------------
template <typename OutT>
__global__ __launch_bounds__(512, 2) void gemm_sc256(
    const __bf16* __restrict__ A, const __bf16* __restrict__ B,
    OutT* __restrict__ C, float* __restrict__ gsum, float alpha)
{
    extern __shared__ __bf16 lds[];    // 128 KiB
    __shared__ float csum[256];
    const int tid = threadIdx.x;
    const int L = blockIdx.x;
    const int per = gridDim.x >> 3;
    const int wrk = (L & 7) * per + (L >> 3);
    const int Lt = wrk % 36;
    const int z  = wrk / 36;
    int tb = (int)((sqrtf(8.f * Lt + 1.f) - 1.f) * 0.5f);
    while ((tb + 1) * (tb + 2) / 2 <= Lt) ++tb;
    while (tb * (tb + 1) / 2 > Lt) --tb;
    const int sb = Lt - tb * (tb + 1) / 2;
    const int n0 = tb * 256;     // t (column)
    const int m0 = sb * 256;     // s (row), sb <= tb

    const __bf16* Ag = A + (long)z * SEQ * HD + (long)m0 * HD;
    const __bf16* Bg = B + (long)z * SEQ * HD + (long)n0 * HD;
    OutT* Cz = C + (long)z * SEQ * SEQ;
    gsum += (long)z * SEQ;

    if (tid < 256) csum[tid] = 0.f;
    __syncthreads();

    f32x4 acc[8][4];
    const f32x4 zero = {0.f, 0.f, 0.f, 0.f};
#pragma unroll
    for (int i = 0; i < 8; ++i)
#pragma unroll
        for (int j = 0; j < 4; ++j) acc[i][j] = zero;

    kloop256(Ag, HD, Bg, HD, HD / 64, lds, tid, acc);

    const int lane = tid & 63, l15 = lane & 15, quad = lane >> 4;
    const int wave = tid >> 6, wr = wave >> 2, wc = wave & 3;
#pragma unroll
    for (int j = 0; j < 4; ++j) {
        const int col = n0 + wc * 64 + j * 16 + l15;
        float part = 0.f;
#pragma unroll
        for (int i = 0; i < 8; ++i) {
#pragma unroll
            for (int rr = 0; rr < 4; ++rr) {
                const int row = m0 + wr * 128 + i * 16 + quad * 4 + rr;
                float v = __expf(acc[i][j][rr] * alpha);
                if (row <= col) part += v;
                Cz[(long)row * SEQ + col] = (OutT)v;
            }
        }
        atomicAdd(&csum[wc * 64 + j * 16 + l15], part);
    }
    __syncthreads();
    if (tid < 256) atomicAdd(&gsum[n0 + tid], csum[tid]);
}

// ---------------------------------------------------------------------------
// Legacy 128x128 GEMM (B-transposed) — still used for the context GEMM
// (CKLIM path) and available for fallback. Double-buffered (R1).
// ---------------------------------------------------------------------------
template <bool TRI, bool CKLIM, bool EXPSUM, typename OutT>
__global__ __launch_bounds__(256) void gemm_bt(
    const __bf16* __restrict__ A, long strideA, int lda,
    const __bf16* __restrict__ B, long strideB, int ldb,
    OutT* __restrict__ C, long strideC, int ldc,
    float* __restrict__ gsum,
    int K, float alpha)
{
    __shared__ __bf16 sA[2][128 * 64];
    __shared__ __bf16 sB[2][128 * 64];
    __shared__ float csum[128];

    const int tid = threadIdx.x;
    const int L = blockIdx.x;
    const int per = gridDim.x >> 3;
    const int wrk = (L & 7) * per + (L >> 3);
    int n0, m0, z;
    if (TRI) {
        const int Lt = wrk % 136;
        z = wrk / 136;
        int tb = (int)((sqrtf(8.f * Lt + 1.f) - 1.f) * 0.5f);
        while ((tb + 1) * (tb + 2) / 2 <= Lt) ++tb;
        while (tb * (tb + 1) / 2 > Lt) --tb;
        const int sb = Lt - tb * (tb + 1) / 2;
        n0 = tb * 128;
        m0 = sb * 128;
    } else {
        n0 = (wrk & 7) * 128;
        m0 = ((wrk >> 3) & 15) * 128;
        z  = wrk >> 7;
    }

    const __bf16* Ag = A + (long)z * strideA + (long)m0 * lda;
    const __bf16* Bg = B + (long)z * strideB + (long)n0 * ldb;
    C += (long)z * strideC;
    if (EXPSUM) {
        gsum += (long)z * SEQ;
        if (tid < 128) csum[tid] = 0.f;
    }

    const int lane = tid & 63;
    const int l15  = lane & 15;
    const int quad = lane >> 4;
    const int wave = tid >> 6;
    const int wm = (wave >> 1) * 64;
    const int wn = (wave & 1) * 64;

    f32x4 acc[4][4];
    const f32x4 zero = {0.f, 0.f, 0.f, 0.f};
#pragma unroll
    for (int i = 0; i < 4; ++i)
#pragma unroll
        for (int j = 0; j < 4; ++j) acc[i][j] = zero;

    const int Kend = CKLIM ? min(K, m0 + 128) : K;

    stage_tile(Ag, lda, sA[0], tid);
    stage_tile(Bg, ldb, sB[0], tid);
    __syncthreads();

    int cur = 0;
    for (int kc = 0; kc < Kend; kc += 64) {
        const int nxt = kc + 64;
        if (nxt < Kend) {
            stage_tile(Ag + nxt, lda, sA[cur ^ 1], tid);
            stage_tile(Bg + nxt, ldb, sB[cur ^ 1], tid);
        }
        mfma_ktile(sA[cur], sB[cur], wm, wn, l15, quad, acc);
        __syncthreads();
        cur ^= 1;
    }

#pragma unroll
    for (int j = 0; j < 4; ++j) {
        const int col = n0 + wn + j * 16 + l15;
        float part = 0.f;
#pragma unroll
        for (int i = 0; i < 4; ++i) {
#pragma unroll
            for (int r = 0; r < 4; ++r) {
                const int row = m0 + wm + i * 16 + quad * 4 + r;
                float v = acc[i][j][r] * alpha;
                if (EXPSUM) {
                    v = __expf(v);
                    if (row <= col) part += v;
                }
                C[(long)row * ldc + col] = (OutT)v;
            }
        }
        if (EXPSUM) atomicAdd(&csum[wn + j * 16 + l15], part);
    }
    if (EXPSUM) {
        __syncthreads();
        if (tid < 128) atomicAdd(&gsum[n0 + tid], csum[tid]);
    }
}

// ---------------------------------------------------------------------------
// Legacy f32-input projection GEMM (fallback path only).
// ---------------------------------------------------------------------------
template <typename TA, typename TW>
__global__ __launch_bounds__(256) void gemm_proj(Proj3 p)
{
    __shared__ __bf16 sA[2][128 * 64];
    __shared__ __bf16 sB[2][128 * 64];

    const int tid = threadIdx.x;
    const int L = blockIdx.x;
    const int per = gridDim.x >> 3;
    const int wrk = (L & 7) * per + (L >> 3);
    const int n0 = (wrk & 7) * 128;
    const int m0 = ((wrk >> 3) & 63) * 128;
    const int z  = wrk >> 9;
    const bool vt = (p.vtmask >> z) & 1;

    const TA* Ag = (const TA*)p.A[z] + (long)m0 * HD;
    const TW* Wg = (const TW*)p.W[z] + (long)n0 * HD;
    const float* bias = p.bias[z];
    __bf16* C = p.C[z];

    const int lane = tid & 63;
    const int l15  = lane & 15;
    const int quad = lane >> 4;
    const int wave = tid >> 6;
    const int wm = (wave >> 1) * 64;
    const int wn = (wave & 1) * 64;

    f32x4 acc[4][4];
    const f32x4 zero = {0.f, 0.f, 0.f, 0.f};
#pragma unroll
    for (int i = 0; i < 4; ++i)
#pragma unroll
        for (int j = 0; j < 4; ++j) acc[i][j] = zero;

    stage_tile(Ag, HD, sA[0], tid);
    stage_tile(Wg, HD, sB[0], tid);
    __syncthreads();

    int cur = 0;
    for (int kc = 0; kc < HD; kc += 64) {
        const int nxt = kc + 64;
        if (nxt < HD) {
            stage_tile(Ag + nxt, HD, sA[cur ^ 1], tid);
            stage_tile(Wg + nxt, HD, sB[cur ^ 1], tid);
        }
        mfma_ktile(sA[cur], sB[cur], wm, wn, l15, quad, acc);
        __syncthreads();
        cur ^= 1;
    }

#pragma unroll
    for (int j = 0; j < 4; ++j) {
        const int col = n0 + wn + j * 16 + l15;
        const float bv = bias[col];
#pragma unroll
        for (int i = 0; i < 4; ++i) {
#pragma unroll
            for (int r = 0; r < 4; ++r) {
                const int row = m0 + wm + i * 16 + quad * 4 + r;
                const float v = acc[i][j][r] + bv;
                if (vt) {
                    C[(((long)(row >> 11) * HD) + col) * SEQ + (row & (SEQ - 1))] = (__bf16)v;
                } else {
                    C[(long)row * HD + col] = (__bf16)v;
                }
            }
        }
    }
}

// ---------------------------------------------------------------------------
// Scale + emit (unchanged).
// ---------------------------------------------------------------------------
template <typename ET>
__global__ __launch_bounds__(256) void scale_emit(
    const ET* __restrict__ E, float* __restrict__ Out,
    const float* __restrict__ csum, __bf16* __restrict__ AT)
{
    __shared__ __bf16 tile[64][65];
    const int b = blockIdx.z;
    const int t0 = blockIdx.x * 128;
    const int s0 = blockIdx.y * 128;
    const ET* Eb = E + (long)b * SEQ * SEQ;
    float* Ob = Out + (long)b * SEQ * SEQ;
    __bf16* Ab = AT + (long)b * SEQ * SEQ;
    const int tid = threadIdx.x;

    if (s0 > t0 + 127) {
        const f32x4 z4 = {0.f, 0.f, 0.f, 0.f};
        const int c4 = (tid & 31) * 4;
        for (int r = tid >> 5; r < 128; r += 8)
            *(f32x4*)&Ob[(long)(s0 + r) * SEQ + t0 + c4] = z4;
        return;
    }

#pragma unroll
    for (int ds = 0; ds < 2; ++ds) {
#pragma unroll
        for (int dt = 0; dt < 2; ++dt) {
            const int ss = s0 + ds * 64, tt = t0 + dt * 64;
            const int c4 = (tid & 15) * 4;
            const int tcol = tt + c4;
            const f32x4 sv = *(const f32x4*)&csum[(long)b * SEQ + tcol];
            f32x4 inv;
#pragma unroll
            for (int k = 0; k < 4; ++k) inv[k] = 1.0f / sv[k];
#pragma unroll
            for (int r0 = 0; r0 < 64; r0 += 16) {
                const int s = ss + r0 + (tid >> 4);
                f32x4 e = load4f(&Eb[(long)s * SEQ + tcol]);
                f32x4 p;
#pragma unroll
                for (int k = 0; k < 4; ++k)
                    p[k] = (s <= tcol + k) ? e[k] * inv[k] : 0.f;
                *(f32x4*)&Ob[(long)s * SEQ + tcol] = p;
#pragma unroll
                for (int k = 0; k < 4; ++k)
                    tile[r0 + (tid >> 4)][c4 + k] = (__bf16)p[k];
            }
            __syncthreads();
            const int tr = tid >> 2;
            const int sc = (tid & 3) * 16;
            __bf16 v[16];
#pragma unroll
            for (int jj = 0; jj < 16; ++jj) v[jj] = tile[sc + jj][tr];
            *(bf16x8*)&Ab[(long)(tt + tr) * SEQ + ss + sc]     = *(bf16x8*)v;
            *(bf16x8*)&Ab[(long)(tt + tr) * SEQ + ss + sc + 8] = *(bf16x8*)(v + 8);
            __syncthreads();
        }
    }
}

// ---------------------------------------------------------------------------
// Batched f32 -> bf16 convert: up to 6 jobs in one dispatch.
// ---------------------------------------------------------------------------
struct CvtJob { const float* in; __bf16* out; int nblk; };
struct Cvt6 { CvtJob j[6]; };
__global__ __launch_bounds__(256) void cvt_bf16(Cvt6 c)
{
    const CvtJob jb = c.j[blockIdx.y];
    if ((int)blockIdx.x >= jb.nblk) return;
    const long i = ((long)blockIdx.x * 256 + threadIdx.x) * 8;
    *(bf16x8*)&jb.out[i] = load8cvt(&jb.in[i]);
}

// ---------------------------------------------------------------------------
extern "C" void kernel_launch(void* const* d_in, const int* in_sizes, int n_in,
                              void* d_out, int out_size, void* d_ws, size_t ws_size,
                              hipStream_t stream)
{
    const float* queries = (const float*)d_in[0];
    const float* keys    = (const float*)d_in[1];
    const float* values  = (const float*)d_in[2];
    const float* Wq = (const float*)d_in[3];
    const float* bq = (const float*)d_in[4];
    const float* Wk = (const float*)d_in[5];
    const float* bk = (const float*)d_in[6];
    const float* Wv = (const float*)d_in[7];
    const float* bv = (const float*)d_in[8];

    const long tokens = (long)NB * SEQ;           // 8192
    const long pe = tokens * HD;                  // elems per 16 MiB buffer
    const size_t SLOT = (size_t)pe * sizeof(__bf16);   // 16 MiB
    const int ABLK = (int)(pe / 2048);            // 4096 cvt blocks per activation
    const int WBLK = WEL / 2048;                  // 512 cvt blocks per weight
    const int LDS256 = 131072;                    // dynamic LDS for 256-tile kernels

    static int attr_done = 0;
    if (!attr_done) {
        hipFuncSetAttribute((const void*)gemm_proj256,
                            hipFuncAttributeMaxDynamicSharedMemorySize, LDS256);
        hipFuncSetAttribute((const void*)gemm_sc256<__bf16>,
                            hipFuncAttributeMaxDynamicSharedMemorySize, LDS256);
        hipFuncSetAttribute((const void*)gemm_sc256<float>,
                            hipFuncAttributeMaxDynamicSharedMemorySize, LDS256);
        attr_done = 1;
    }

    float* outCtx  = (float*)d_out;               // [4][2048][1024] f32
    float* outAttn = outCtx + tokens * HD;        // [4][2048][2048] f32
    float* colsum = outCtx;                       // 32 KB, dead until ctx GEMM
    __bf16* wb = (__bf16*)outAttn;                // bf16 weights: dead-at-start
    __bf16* Wqb = wb, *Wkb = wb + WEL, *Wvb = wb + 2 * WEL;

    const dim3 blk(256);
    const dim3 blk512(512);
    hipMemsetAsync(colsum, 0, (size_t)NB * SEQ * sizeof(float), stream);

    char* w = (char*)d_ws;
    __bf16 *qp, *kp, *vT, *attnT;

    bool ebig = false;                 // E stored as bf16 in ws?
    __bf16* Ebf = nullptr;

    if (ws_size >= 6 * SLOT) {
        __bf16* xq = (__bf16*)w;
        __bf16* xk = (__bf16*)(w + SLOT);
        __bf16* xv = (__bf16*)(w + 2 * SLOT);
        qp = (__bf16*)(w + 3 * SLOT);
        kp = (__bf16*)(w + 4 * SLOT);
        vT = (__bf16*)(w + 5 * SLOT);
        Ebf = (__bf16*)w;
        attnT = (__bf16*)(w + 2 * SLOT);
        ebig = true;

        Cvt6 cv = {{{queries, xq, ABLK}, {keys, xk, ABLK}, {values, xv, ABLK},
                    {Wq, Wqb, WBLK}, {Wk, Wkb, WBLK}, {Wv, Wvb, WBLK}}};
        cvt_bf16<<<dim3(ABLK, 6), blk, 0, stream>>>(cv);
        Proj3 pj = {{xq, xk, xv}, {Wqb, Wkb, Wvb}, {bq, bk, bv}, {qp, kp, vT}, 4};
        gemm_proj256<<<dim3(128 * 3), blk512, LDS256, stream>>>(pj);
    } else if (ws_size >= 4 * SLOT) {
        __bf16* x0 = (__bf16*)w;
        qp = (__bf16*)(w + SLOT);
        kp = (__bf16*)(w + 2 * SLOT);
        __bf16* x1 = (__bf16*)(w + 3 * SLOT);
        vT = x1;
        attnT = (__bf16*)d_ws;

        Cvt6 cv = {{{queries, x0, ABLK}, {keys, x1, ABLK},
                    {Wq, Wqb, WBLK}, {Wk, Wkb, WBLK}, {Wv, Wvb, WBLK},
                    {nullptr, nullptr, 0}}};
        cvt_bf16<<<dim3(ABLK, 5), blk, 0, stream>>>(cv);
        Proj3 pqk = {{x0, x1, nullptr}, {Wqb, Wkb, nullptr}, {bq, bk, nullptr},
                     {qp, kp, nullptr}, 0};
        gemm_proj256<<<dim3(128 * 2), blk512, LDS256, stream>>>(pqk);
        Cvt6 cvv = {{{values, x0, ABLK}, {nullptr, nullptr, 0}, {nullptr, nullptr, 0},
                     {nullptr, nullptr, 0}, {nullptr, nullptr, 0}, {nullptr, nullptr, 0}}};
        cvt_bf16<<<dim3(ABLK, 1), blk, 0, stream>>>(cvv);
        Proj3 pv = {{x0, nullptr, nullptr}, {Wvb, nullptr, nullptr},
                    {bv, nullptr, nullptr}, {vT, nullptr, nullptr}, 1};
        gemm_proj256<<<dim3(128), blk512, LDS256, stream>>>(pv);
    } else {
        qp = (__bf16*)w;
        kp = (__bf16*)(w + SLOT);
        vT = (__bf16*)(w + 2 * SLOT);
        attnT = (__bf16*)d_ws;
        Proj3 pj = {{queries, keys, values}, {Wq, Wk, Wv}, {bq, bk, bv},
                    {qp, kp, vT}, 4};
        gemm_proj<float, float><<<dim3(512 * 3), blk, 0, stream>>>(pj);
    }

    // scores + fused exp/colsum: E[b][s][t] = exp(<k_s,q_t>/32)
    // grid 144 = 4 x 36 causal 256-blocks, XCD-remapped in-kernel
    if (ebig) {
        gemm_sc256<__bf16><<<dim3(144), blk512, LDS256, stream>>>(
            kp, qp, Ebf, colsum, 0.03125f);
        scale_emit<__bf16><<<dim3(SEQ / 128, SEQ / 128, NB), blk, 0, stream>>>(
            Ebf, outAttn, colsum, attnT);
    } else {
        gemm_sc256<float><<<dim3(144), blk512, LDS256, stream>>>(
            kp, qp, outAttn, colsum, 0.03125f);
        scale_emit<float><<<dim3(SEQ / 128, SEQ / 128, NB), blk, 0, stream>>>(
            outAttn, outAttn, colsum, attnT);
    }

    // context: C[b][t][h] = sum_{s<=t} attnT[t][s] * vT[h][s]
    // 1-D grid 512 = 4 x (8 n x 16 m), XCD-remapped in-kernel
    gemm_bt<false, true, false, float><<<dim3(512), blk, 0, stream>>>(
        attnT, (long)SEQ * SEQ, SEQ, vT, (long)HD * SEQ, SEQ,
        outCtx, (long)SEQ * HD, HD, nullptr, SEQ, 1.0f);
}